// Round 1
// baseline (22997.150 us; speedup 1.0000x reference)
//
#include <hip/hip_runtime.h>
#include <cstdint>

#define Bb 32
#define Cc 512
#define Nn 384
#define Vv 600
#define Ee 256
#define Dd 512
#define Tt 192
#define Ss 191
#define EOS_TOK 130
#define BD (Bb*Dd)          // 16384
#define G4 2048             // 4*D
#define KREC 1280           // E + D + D
#define KSPLIT 8
#define KCH 160             // KREC/KSPLIT

// ---- ws layout (float offsets) ----
#define OFF_TOK   0          // int tok[Ss*Bb] in first 8192 float slots
#define OFF_PART  8192                       // KSPLIT*Bb*G4 = 524288
#define OFF_WV    (OFF_PART + 524288)        // Bb*Nn*Dd = 6291456
#define OFF_HX    (OFF_WV + 6291456)
#define OFF_CX    (OFF_HX + 16384)
#define OFF_Q     (OFF_CX + 16384)
#define OFF_CTX   (OFF_Q + 16384)
#define OFF_SC    (OFF_CTX + 16384)
#define OFF_OBUF  (OFF_SC + 16384)           // (Ss+1)*BD = 3145728

#define LOGITS_SZ (Bb*Ss*Vv)  // 3667200

__device__ __forceinline__ float sigm_(float x) {
    float e = __expf(-x);
    return __builtin_amdgcn_rcpf(1.0f + e);
}
__device__ __forceinline__ float tanh_(float x) {
    float xc = fminf(15.0f, fmaxf(-15.0f, x));
    float e = __expf(2.0f * xc);
    return (e - 1.0f) * __builtin_amdgcn_rcpf(e + 1.0f);
}

// S0: zero state, precompute teacher-forcing token sequence (with EOS masking).
__global__ void k_setup(const int* __restrict__ tgt, float* hx, float* cx,
                        float* obuf0, int* tok) {
    int idx = blockIdx.x * 256 + threadIdx.x;
    if (idx < BD) { hx[idx] = 0.f; cx[idx] = 0.f; obuf0[idx] = 0.f; }
    if (blockIdx.x == 0) {
        __shared__ int is64;
        if (threadIdx.x == 0) {
            // detect int64 tokens passed as raw 8-byte ints (high words all 0)
            int a = 1;
            for (int k = 0; k < 32; ++k) if (tgt[2*k+1] != 0) a = 0;
            is64 = a;
        }
        __syncthreads();
        int b = threadIdx.x;
        if (b < Bb) {
            int fin = 0;
            tok[0*Bb + b] = 0;  // sos
            for (int s = 1; s < Ss; ++s) {
                int li = b * Tt + s;
                int nt = is64 ? tgt[2*li] : tgt[li];
                if (nt == EOS_TOK) fin = 1;
                tok[s*Bb + b] = fin ? 0 : nt;
            }
        }
    }
}

// S1: Wv[b,n,d] = sum_c enc[b,n,c] * W_v[c,d]   (one-time)
__global__ void k_wv(const float* __restrict__ enc, const float* __restrict__ Wv_w,
                     float* __restrict__ Wv) {
    int b = blockIdx.x / 24, nt = blockIdx.x % 24, n0 = nt * 16;
    __shared__ float encL[16 * 512];
    for (int i = 0; i < 32; ++i) {
        int e = threadIdx.x + i * 256;
        int ni = e >> 9, c = e & 511;
        encL[e] = enc[((b * Nn) + (n0 + ni)) * Cc + c];
    }
    __syncthreads();
    int d0 = threadIdx.x, d1 = threadIdx.x + 256;
    float a0[16], a1[16];
#pragma unroll
    for (int i = 0; i < 16; ++i) { a0[i] = 0.f; a1[i] = 0.f; }
    for (int c = 0; c < 512; ++c) {
        float w0 = Wv_w[c * Dd + d0], w1 = Wv_w[c * Dd + d1];
#pragma unroll
        for (int i = 0; i < 16; ++i) {
            float ev = encL[i * 512 + c];
            a0[i] += ev * w0; a1[i] += ev * w1;
        }
    }
#pragma unroll
    for (int i = 0; i < 16; ++i) {
        Wv[((b * Nn) + (n0 + i)) * Dd + d0] = a0[i];
        Wv[((b * Nn) + (n0 + i)) * Dd + d1] = a1[i];
    }
}

// K1: gates partials, 8-way K-split. grid = 256 blocks (32 j-tiles x 8 k-slices)
__global__ void k_gates(const float* __restrict__ W_ih, const float* __restrict__ W_hh,
                        const float* __restrict__ emb, const int* __restrict__ tok,
                        const float* __restrict__ o_prev, const float* __restrict__ hx,
                        float* __restrict__ part, int t) {
    int jt = blockIdx.x & 31, ks = blockIdx.x >> 5;
    int j0 = jt * 64;
    __shared__ float xL[KCH * 32];  // [k][b]
    for (int i = 0; i < KCH * 32 / 256; ++i) {   // 20 iters
        int e = threadIdx.x + i * 256;
        int b = e / KCH, k = e % KCH;
        int kg = ks * KCH + k;
        float val;
        if (kg < Ee)            val = emb[tok[t * Bb + b] * Ee + kg];
        else if (kg < Ee + Dd)  val = o_prev[b * Dd + (kg - Ee)];
        else                    val = hx[b * Dd + (kg - Ee - Dd)];
        xL[k * 32 + b] = val;
    }
    __syncthreads();
    int jl = threadIdx.x & 63, bg = threadIdx.x >> 6;
    int j = j0 + jl;
    float acc[8];
#pragma unroll
    for (int i = 0; i < 8; ++i) acc[i] = 0.f;
    for (int k = 0; k < KCH; ++k) {
        int kg = ks * KCH + k;
        const float* wrow = (kg < Ee + Dd) ? (W_ih + (size_t)kg * G4)
                                           : (W_hh + (size_t)(kg - Ee - Dd) * G4);
        float w = wrow[j];
        float4 xa = *(const float4*)&xL[k * 32 + bg * 8];
        float4 xb = *(const float4*)&xL[k * 32 + bg * 8 + 4];
        acc[0] += xa.x * w; acc[1] += xa.y * w; acc[2] += xa.z * w; acc[3] += xa.w * w;
        acc[4] += xb.x * w; acc[5] += xb.y * w; acc[6] += xb.z * w; acc[7] += xb.w * w;
    }
#pragma unroll
    for (int i = 0; i < 8; ++i)
        part[ks * (Bb * G4) + (bg * 8 + i) * G4 + j] = acc[i];
}

// K2: reduce partials, LSTM pointwise, zero ctx. grid 64x256
__global__ void k_lstm(const float* __restrict__ part, const float* __restrict__ b_ih,
                       const float* __restrict__ b_hh, float* __restrict__ hx,
                       float* __restrict__ cx, float* __restrict__ ctx) {
    int idx = blockIdx.x * 256 + threadIdx.x;
    int b = idx >> 9, d = idx & 511;
    float g[4];
#pragma unroll
    for (int gi = 0; gi < 4; ++gi) {
        int j = gi * Dd + d;
        float s = b_ih[j] + b_hh[j];
#pragma unroll
        for (int ks = 0; ks < KSPLIT; ++ks)
            s += part[ks * (Bb * G4) + b * G4 + j];
        g[gi] = s;
    }
    float i_ = sigm_(g[0]), f_ = sigm_(g[1]), gg = tanh_(g[2]), oo = sigm_(g[3]);
    float c = f_ * cx[idx] + i_ * gg;
    cx[idx] = c;
    hx[idx] = oo * tanh_(c);
    ctx[idx] = 0.f;
}

// K3a: q = hx @ W_h. grid 64x256
__global__ void k_q(const float* __restrict__ hx, const float* __restrict__ W_h,
                    float* __restrict__ q) {
    int idx = blockIdx.x * 256 + threadIdx.x;
    int b = idx >> 9, d = idx & 511;
    float acc = 0.f;
    for (int k = 0; k < Dd; ++k)
        acc += hx[b * Dd + k] * W_h[k * Dd + d];
    q[idx] = acc;
}

// K3b: scores. one wave per (b,n). grid 3072x256
__global__ void k_score(const float* __restrict__ q, const float* __restrict__ Wv,
                        const float* __restrict__ vv, float* __restrict__ sc) {
    int wid = (blockIdx.x * 256 + threadIdx.x) >> 6;
    int lane = threadIdx.x & 63;
    int b = wid / Nn, n = wid % Nn;
    const float* wvp = Wv + (size_t)(b * Nn + n) * Dd;
    const float* qb = q + b * Dd;
    float acc = 0.f;
#pragma unroll
    for (int i = 0; i < 8; ++i) {
        int d = lane + i * 64;
        acc += vv[d] * tanh_(qb[d] + wvp[d]);
    }
#pragma unroll
    for (int off = 32; off > 0; off >>= 1)
        acc += __shfl_down(acc, off, 64);
    if (lane == 0) sc[b * Nn + n] = acc;
}

// K4: softmax (redundant per slice) + alpha out + context partial via atomics.
// grid 256 blocks = (b, slice of 48 n)
__global__ void k_ctx(const float* __restrict__ sc, const float* __restrict__ enc,
                      float* __restrict__ ctx, float* __restrict__ alpha_out, int t) {
    int b = blockIdx.x >> 3, sl = blockIdx.x & 7;
    __shared__ float eL[Nn];
    __shared__ float red[256];
    __shared__ float aL[48];
    int tid = threadIdx.x;
    float m = -1e30f;
    for (int n = tid; n < Nn; n += 256) m = fmaxf(m, sc[b * Nn + n]);
    red[tid] = m; __syncthreads();
    for (int s = 128; s > 0; s >>= 1) {
        if (tid < s) red[tid] = fmaxf(red[tid], red[tid + s]);
        __syncthreads();
    }
    m = red[0]; __syncthreads();
    float ps = 0.f;
    for (int n = tid; n < Nn; n += 256) {
        float e = __expf(sc[b * Nn + n] - m);
        eL[n] = e; ps += e;
    }
    red[tid] = ps; __syncthreads();
    for (int s = 128; s > 0; s >>= 1) {
        if (tid < s) red[tid] += red[tid + s];
        __syncthreads();
    }
    float inv = 1.0f / red[0];
    int n0 = sl * 48;
    if (tid < 48) {
        float a = eL[n0 + tid] * inv;
        aL[tid] = a;
        alpha_out[b * (Ss * Nn) + t * Nn + n0 + tid] = a;
    }
    __syncthreads();
    int c0 = tid, c1 = tid + 256;
    float acc0 = 0.f, acc1 = 0.f;
    for (int i = 0; i < 48; ++i) {
        float a = aL[i];
        const float* er = enc + (size_t)((b * Nn) + (n0 + i)) * Cc;
        acc0 += a * er[c0];
        acc1 += a * er[c1];
    }
    atomicAdd(&ctx[b * Cc + c0], acc0);
    atomicAdd(&ctx[b * Cc + c1], acc1);
}

// K5: o_t = tanh([hx|ctx] @ W_c + b_c). grid 64x256
__global__ void k_out(const float* __restrict__ hx, const float* __restrict__ ctx,
                      const float* __restrict__ W_c, const float* __restrict__ b_c,
                      float* __restrict__ o_t) {
    int idx = blockIdx.x * 256 + threadIdx.x;
    int b = idx >> 9, d = idx & 511;
    float acc = b_c[d];
    for (int k = 0; k < Dd; ++k)
        acc += hx[b * Dd + k] * W_c[k * Dd + d];
    for (int k = 0; k < Cc; ++k)
        acc += ctx[b * Cc + k] * W_c[(Dd + k) * Dd + d];
    o_t[idx] = tanh_(acc);
}

// K6: deferred logits GEMM. grid 768 blocks = (b, t-tile of 8)
__global__ void k_logits(const float* __restrict__ obuf, const float* __restrict__ W_out,
                         const float* __restrict__ b_out, float* __restrict__ out_logits) {
    int b = blockIdx.x / 24, tt = blockIdx.x % 24;
    int t0 = tt * 8;
    int tmax = min(8, Ss - t0);
    __shared__ float oL[8 * 512];
    int tid = threadIdx.x;
    for (int i = 0; i < 16; ++i) {
        int e = tid + i * 256;
        int ti = e >> 9, d = e & 511;
        oL[e] = (ti < tmax) ? obuf[(size_t)(t0 + ti + 1) * BD + b * Dd + d] : 0.f;
    }
    __syncthreads();
    int v0 = tid, v1 = tid + 256, v2 = tid + 512;
    bool h2 = (v2 < Vv);
    int v2c = h2 ? v2 : 0;
    float acc[3][8];
#pragma unroll
    for (int s = 0; s < 3; ++s)
#pragma unroll
        for (int ti = 0; ti < 8; ++ti) acc[s][ti] = 0.f;
    for (int d = 0; d < 512; ++d) {
        float w0 = W_out[d * Vv + v0];
        float w1 = W_out[d * Vv + v1];
        float w2 = W_out[d * Vv + v2c];
#pragma unroll
        for (int ti = 0; ti < 8; ++ti) {
            float o = oL[ti * 512 + d];
            acc[0][ti] += o * w0; acc[1][ti] += o * w1; acc[2][ti] += o * w2;
        }
    }
    for (int ti = 0; ti < tmax; ++ti) {
        size_t base = (size_t)b * (Ss * Vv) + (size_t)(t0 + ti) * Vv;
        out_logits[base + v0] = acc[0][ti] + b_out[v0];
        out_logits[base + v1] = acc[1][ti] + b_out[v1];
        if (h2) out_logits[base + v2] = acc[2][ti] + b_out[v2];
    }
}

extern "C" void kernel_launch(void* const* d_in, const int* in_sizes, int n_in,
                              void* d_out, int out_size, void* d_ws, size_t ws_size,
                              hipStream_t stream) {
    const float* enc   = (const float*)d_in[0];
    const int*   tgt   = (const int*)d_in[1];
    const float* emb   = (const float*)d_in[2];
    const float* W_ih  = (const float*)d_in[3];
    const float* b_ih  = (const float*)d_in[4];
    const float* W_hh  = (const float*)d_in[5];
    const float* b_hh  = (const float*)d_in[6];
    const float* W_h   = (const float*)d_in[7];
    const float* W_v   = (const float*)d_in[8];
    const float* vv    = (const float*)d_in[9];
    const float* W_c   = (const float*)d_in[10];
    const float* b_c   = (const float*)d_in[11];
    const float* W_out = (const float*)d_in[12];
    const float* b_out = (const float*)d_in[13];

    float* wsf = (float*)d_ws;
    int*   tok = (int*)d_ws;                 // first 8192 float slots
    float* part = wsf + OFF_PART;
    float* Wv   = wsf + OFF_WV;
    float* hx   = wsf + OFF_HX;
    float* cx   = wsf + OFF_CX;
    float* q    = wsf + OFF_Q;
    float* ctx  = wsf + OFF_CTX;
    float* sc   = wsf + OFF_SC;
    float* obuf = wsf + OFF_OBUF;

    float* out_logits = (float*)d_out;
    float* out_alphas = (float*)d_out + LOGITS_SZ;

    k_setup<<<64, 256, 0, stream>>>(tgt, hx, cx, obuf, tok);
    k_wv<<<768, 256, 0, stream>>>(enc, W_v, Wv);

    for (int t = 0; t < Ss; ++t) {
        k_gates<<<256, 256, 0, stream>>>(W_ih, W_hh, emb, tok, obuf + (size_t)t * BD,
                                         hx, part, t);
        k_lstm<<<64, 256, 0, stream>>>(part, b_ih, b_hh, hx, cx, ctx);
        k_q<<<64, 256, 0, stream>>>(hx, W_h, q);
        k_score<<<3072, 256, 0, stream>>>(q, Wv, vv, sc);
        k_ctx<<<256, 256, 0, stream>>>(sc, enc, ctx, out_alphas, t);
        k_out<<<64, 256, 0, stream>>>(hx, ctx, W_c, b_c, obuf + (size_t)(t + 1) * BD);
    }
    k_logits<<<768, 256, 0, stream>>>(obuf, W_out, b_out, out_logits);
}